// Round 1
// baseline (170.452 us; speedup 1.0000x reference)
//
#include <hip/hip_runtime.h>
#include <math.h>

#define NQ 6
#define SDIM 64
#define NLAYERS 3
#define QBATCH 262144
#define NGATES (NLAYERS * NQ)

// One thread = one sample. Statevector (64 complex) lives in registers.
// The 18 fused variational gates (RZ*RY*RX per layer/qubit, shared across
// batch) are computed once per block by lanes 0..17 into LDS and broadcast.
__global__ __launch_bounds__(256) void qnn_fused_kernel(
    const float* __restrict__ x,
    const float* __restrict__ pre_w1, const float* __restrict__ pre_b1,
    const float* __restrict__ pre_w2, const float* __restrict__ pre_b2,
    const float* __restrict__ qw,
    const float* __restrict__ post_w1, const float* __restrict__ post_b1,
    const float* __restrict__ post_w2, const float* __restrict__ post_b2,
    float* __restrict__ out)
{
    __shared__ float gs[NGATES * 8];
    {
        const int g = threadIdx.x;
        if (g < NGATES) {
            const int p = g * 3;
            float s0 = sinf(qw[p+0] * 0.5f), c0 = cosf(qw[p+0] * 0.5f);
            float s1 = sinf(qw[p+1] * 0.5f), c1 = cosf(qw[p+1] * 0.5f);
            float s2 = sinf(qw[p+2] * 0.5f), c2 = cosf(qw[p+2] * 0.5f);
            // M = RY(t1)*RX(t0)
            const float m00r =  c1*c0, m00i =  s1*s0;
            const float m01r = -s1*c0, m01i = -c1*s0;
            const float m10r =  s1*c0, m10i = -c1*s0;
            const float m11r =  c1*c0, m11i = -s1*s0;
            // G = RZ(t2)*M : row0 *= (c2 - i s2), row1 *= (c2 + i s2)
            float* o = gs + g*8;
            o[0] = c2*m00r + s2*m00i;  o[1] = c2*m00i - s2*m00r;
            o[2] = c2*m01r + s2*m01i;  o[3] = c2*m01i - s2*m01r;
            o[4] = c2*m10r - s2*m10i;  o[5] = c2*m10i + s2*m10r;
            o[6] = c2*m11r - s2*m11i;  o[7] = c2*m11i + s2*m11r;
        }
    }
    __syncthreads();

    const int tid = blockIdx.x * blockDim.x + threadIdx.x;
    const float4 xv = reinterpret_cast<const float4*>(x)[tid];

    // --- pre-net: h = relu(x @ w1 + b1) ---
    float h[16];
    #pragma unroll
    for (int j = 0; j < 16; ++j) {
        float a = pre_b1[j];
        a = fmaf(xv.x, pre_w1[0*16+j], a);
        a = fmaf(xv.y, pre_w1[1*16+j], a);
        a = fmaf(xv.z, pre_w1[2*16+j], a);
        a = fmaf(xv.w, pre_w1[3*16+j], a);
        h[j] = fmaxf(a, 0.f);
    }

    // --- encoding: product state of H*RY(angle_q)|0> columns (all real) ---
    float re[SDIM], im[SDIM];
    re[0] = 1.f;
    #pragma unroll
    for (int q = 0; q < NQ; ++q) {
        float a = pre_b2[q];
        #pragma unroll
        for (int j = 0; j < 16; ++j) a = fmaf(h[j], pre_w2[j*NQ+q], a);
        const float ang = tanhf(a) * 0.5f;
        const float c = __cosf(ang), s = __sinf(ang);
        const float v0 = (c - s) * 0.70710678118654752440f;
        const float v1 = (c + s) * 0.70710678118654752440f;
        #pragma unroll
        for (int i = 0; i < (1 << q); ++i) {
            re[i | (1 << q)] = re[i] * v1;
            re[i] = re[i] * v0;
        }
    }
    #pragma unroll
    for (int i = 0; i < SDIM; ++i) im[i] = 0.f;

    // --- variational layers ---
    #pragma unroll
    for (int layer = 0; layer < NLAYERS; ++layer) {
        // CX chain (c=q -> t=q+1): pure register permutation, free after unroll
        #pragma unroll
        for (int c = 0; c < NQ - 1; ++c) {
            const int t = c + 1;
            #pragma unroll
            for (int i = 0; i < SDIM; ++i) {
                if (((i >> c) & 1) && !((i >> t) & 1)) {
                    const int j = i | (1 << t);
                    const float tr = re[i]; re[i] = re[j]; re[j] = tr;
                    const float ti = im[i]; im[i] = im[j]; im[j] = ti;
                }
            }
        }
        // fused RZ*RY*RX general 2x2 complex gate per qubit
        #pragma unroll
        for (int q = 0; q < NQ; ++q) {
            const float* gp = gs + (layer*NQ + q)*8;
            const float g00r = gp[0], g00i = gp[1], g01r = gp[2], g01i = gp[3];
            const float g10r = gp[4], g10i = gp[5], g11r = gp[6], g11i = gp[7];
            #pragma unroll
            for (int i0 = 0; i0 < SDIM; ++i0) {
                if ((i0 >> q) & 1) continue;
                const int i1 = i0 | (1 << q);
                const float r0 = re[i0], u0 = im[i0];
                const float r1 = re[i1], u1 = im[i1];
                re[i0] = g00r*r0 - g00i*u0 + g01r*r1 - g01i*u1;
                im[i0] = g00r*u0 + g00i*r0 + g01r*u1 + g01i*r1;
                re[i1] = g10r*r0 - g10i*u0 + g11r*r1 - g11i*u1;
                im[i1] = g10r*u0 + g10i*r0 + g11r*u1 + g11i*r1;
            }
        }
    }

    // --- probabilities (reuse re[]) ---
    #pragma unroll
    for (int i = 0; i < SDIM; ++i) re[i] = fmaf(re[i], re[i], im[i]*im[i]);

    // --- per-qubit Z expectations ---
    float ex[NQ];
    #pragma unroll
    for (int q = 0; q < NQ; ++q) {
        float acc = 0.f;
        #pragma unroll
        for (int i = 0; i < SDIM; ++i)
            acc = ((i >> q) & 1) ? (acc - re[i]) : (acc + re[i]);
        ex[q] = acc;
    }

    // --- post-net ---
    float h2[16];
    #pragma unroll
    for (int j = 0; j < 16; ++j) {
        float a = post_b1[j];
        #pragma unroll
        for (int q = 0; q < NQ; ++q) a = fmaf(ex[q], post_w1[q*16+j], a);
        h2[j] = fmaxf(a, 0.f);
    }
    float o0 = post_b2[0], o1 = post_b2[1], o2 = post_b2[2], o3 = post_b2[3];
    #pragma unroll
    for (int j = 0; j < 16; ++j) {
        o0 = fmaf(h2[j], post_w2[j*4+0], o0);
        o1 = fmaf(h2[j], post_w2[j*4+1], o1);
        o2 = fmaf(h2[j], post_w2[j*4+2], o2);
        o3 = fmaf(h2[j], post_w2[j*4+3], o3);
    }
    reinterpret_cast<float4*>(out)[tid] = make_float4(o0, o1, o2, o3);
}

extern "C" void kernel_launch(void* const* d_in, const int* in_sizes, int n_in,
                              void* d_out, int out_size, void* d_ws, size_t ws_size,
                              hipStream_t stream) {
    const float* x       = (const float*)d_in[0];
    const float* pre_w1  = (const float*)d_in[1];
    const float* pre_b1  = (const float*)d_in[2];
    const float* pre_w2  = (const float*)d_in[3];
    const float* pre_b2  = (const float*)d_in[4];
    const float* qw      = (const float*)d_in[5];
    const float* post_w1 = (const float*)d_in[6];
    const float* post_b1 = (const float*)d_in[7];
    const float* post_w2 = (const float*)d_in[8];
    const float* post_b2 = (const float*)d_in[9];
    float* out = (float*)d_out;

    const int block = 256;
    const int grid = QBATCH / block;  // 262144 / 256 = 1024
    qnn_fused_kernel<<<grid, block, 0, stream>>>(
        x, pre_w1, pre_b1, pre_w2, pre_b2, qw,
        post_w1, post_b1, post_w2, post_b2, out);
}